// Round 6
// baseline (508.501 us; speedup 1.0000x reference)
//
#include <hip/hip_runtime.h>
#include <hip/hip_bf16.h>

// Problem constants (from reference setup_inputs)
#define NB   8
#define NN   16384
#define NK   9
#define NCF  64          // feature channels
#define NCIN 66          // 2 + 64 concat channels
#define NCO  64
#define JTOT (NCIN * NK) // 594
#define KPAD 608         // 19 * 32 (MFMA K-steps)
#define ROWE 610         // LDS wf row length in bf16 elems (odd dword stride -> conflict-free)
#define ROWU (ROWE / 2)  // 305 uints per row
#define MT   32          // points per block
#define CHC  4           // feature channels per staging chunk (was 8)
#define NCHUNK (NCF / CHC)        // 16 chunks
#define NSTG 3                    // triple-buffered stage -> prefetch depth 2
#define ROWB (MT * NK * 4)        // 1152 B per staged channel row
#define TRC  (CHC * ROWB / 16)    // 288 16B transfers per chunk (4.5 wave-instrs)

typedef __attribute__((ext_vector_type(8))) short frag8;  // 8 bf16 (4 VGPRs)
typedef __attribute__((ext_vector_type(4))) float frag4;  // 4 fp32 acc

__device__ __forceinline__ float leakyf(float x) { return fmaxf(x, 0.1f * x); }

// bf16 RNE — the R2/R5-proven numerics path (absmax 0.125). All math below is
// bit-identical to the 474.8/471.7 µs kernels; ONLY the staging schedule changed.
__device__ __forceinline__ unsigned short f2bf(float x) {
  __hip_bfloat16 h = __float2bfloat16(x);
  unsigned short us;
  __builtin_memcpy(&us, &h, 2);
  return us;
}

// Repack lin_w [64][594] fp32 (row co, col o*66+c) into bf16 lb[co][j], j = c*9+o, zero-padded to 608.
__global__ void prep_lb_kernel(const float* __restrict__ lin_w, unsigned short* __restrict__ lb) {
  int idx = blockIdx.x * 256 + threadIdx.x;
  if (idx >= NCO * KPAD) return;
  int co = idx / KPAD;
  int j  = idx - co * KPAD;
  float v = 0.f;
  if (j < JTOT) {
    int c = j / NK;
    int o = j - c * NK;
    v = lin_w[co * JTOT + o * NCIN + c];
  }
  lb[idx] = f2bf(v);
}

__global__ __launch_bounds__(256) void pointconv_kernel(
    const float* __restrict__ xy,   // [8][2][16384][9]
    const float* __restrict__ feat, // [8][64][16384][9]
    const float* __restrict__ w1,   // [9][2]
    const float* __restrict__ b1,   // [9]
    const float* __restrict__ w2,   // [9][9]
    const float* __restrict__ b2,   // [9]
    const unsigned short* __restrict__ lb, // bf16 [64][608]
    const float* __restrict__ lin_b,       // [64]
    float* __restrict__ out) {             // [8][64][16384]
  __shared__ unsigned short wfs[MT * ROWE];   // 39,040 B
  __shared__ float stage[NSTG][CHC * MT * NK];// 3 x 4,608 B = 13,824 B
  // total LDS 52,864 B -> 3 blocks/CU (was 57,472 -> 2)

  const int t    = threadIdx.x;
  const int p    = t & 31;          // point within tile
  const int g    = t >> 5;          // channel group 0..7
  const int lane = t & 63;
  const int wvid = t >> 6;          // wave id 0..3
  const int b    = blockIdx.x >> 9; // 512 tiles per batch
  const int n0   = (blockIdx.x & 511) << 5;
  const int n    = n0 + p;

  // ---- Async staging: per chunk = 4 feat channel-rows (4 x 1152 B = 288
  // 16B slots = 4 full wave-instrs + 1 half). Wave w issues instr i=w; wave 0
  // additionally issues the half-instr (lanes 0..31). Per-chunk DMA count is
  // therefore compile-time per wave: wave0=2, waves1-3=1 -> counted vmcnt. ----
  auto stage_chunk = [&](int ch, float* dst) {
    const char* gb = (const char*)feat +
        (((size_t)b * NCF + ch * CHC) * NN + (size_t)n0) * (NK * 4);
    {
      unsigned j   = wvid * 64u + lane;      // slots 0..255
      unsigned cl  = j / 72u;                // channel within chunk
      unsigned rem = j - cl * 72u;           // 16B-slot within the 1152B row
      const char* gp = gb + (size_t)cl * ((size_t)NN * NK * 4) + rem * 16;
      const char* lp = (const char*)dst + wvid * 1024;  // wave-uniform base
      __builtin_amdgcn_global_load_lds(
          (const __attribute__((address_space(1))) unsigned int*)gp,
          (__attribute__((address_space(3))) unsigned int*)lp,
          16, 0, 0);
    }
    if (wvid == 0 && lane < 32) {            // half-instr: slots 256..287
      unsigned j   = 256u + lane;
      unsigned cl  = j / 72u;                // = 3
      unsigned rem = j - cl * 72u;
      const char* gp = gb + (size_t)cl * ((size_t)NN * NK * 4) + rem * 16;
      const char* lp = (const char*)dst + 4096;
      __builtin_amdgcn_global_load_lds(
          (const __attribute__((address_space(1))) unsigned int*)gp,
          (__attribute__((address_space(3))) unsigned int*)lp,
          16, 0, 0);
    }
  };

  // ---- xy loads FIRST, so the compiler's wait-for-xy (FIFO vmcnt) does not
  // drain the prefetch DMA issued after them. ----
  float x0[9], x1[9];
  {
    const float* x0p = xy + (((size_t)b * 2 + 0) * NN + n) * NK;
    const float* x1p = xy + (((size_t)b * 2 + 1) * NN + n) * NK;
#pragma unroll
    for (int k = 0; k < NK; ++k) { x0[k] = x0p[k]; x1[k] = x1p[k]; }
  }

  stage_chunk(0, stage[0]);  // chunks 0,1 in flight under WeightNet (~2100 cyc)
  stage_chunk(1, stage[1]);

  // ---- Phase 1a: WeightNet -> wv[9][9] (registers; math identical) ----
  float wv[9][9];
#pragma unroll
  for (int k = 0; k < NK; ++k) {
    float h[9];
#pragma unroll
    for (int o = 0; o < 9; ++o)
      h[o] = leakyf(w1[2 * o] * x0[k] + w1[2 * o + 1] * x1[k] + b1[o]);
#pragma unroll
    for (int o = 0; o < 9; ++o) {
      float s = b2[o];
#pragma unroll
      for (int o2 = 0; o2 < 9; ++o2) s += w2[o * 9 + o2] * h[o2];
      wv[o][k] = leakyf(s);
    }
  }

  // ---- xy channels (concat c=0,1) from registers; zero-pad tail ----
  if (g == 0) {
#pragma unroll
    for (int cc = 0; cc < 2; ++cc) {
#pragma unroll
      for (int o = 0; o < 9; ++o) {
        float s = wv[o][0] * (cc ? x1[0] : x0[0]);
#pragma unroll
        for (int k = 1; k < NK; ++k) s += wv[o][k] * (cc ? x1[k] : x0[k]);
        wfs[p * ROWE + cc * 9 + o] = f2bf(s);
      }
    }
  }
  if (g == 1) {
#pragma unroll
    for (int m = 0; m < KPAD - JTOT; ++m) wfs[p * ROWE + JTOT + m] = 0;
  }

  // ---- Phase 1b: T3/T4 pipeline. Epoch ch: [counted vmcnt; s_barrier;
  // issue(ch+2); compute(ch)]. Race argument: everything concurrent within
  // one barrier epoch touches buf[(ch+2)%3] (DMA writes) and buf[ch%3]
  // (reads) — distinct mod 3. vmcnt BEFORE the barrier publishes chunk ch
  // from every wave (each wave's own count is compile-time: w0 keeps its 2
  // newest, others keep 1). No global-memory ops exist inside the loop, so
  // vmcnt counts only staging DMA. Loads for chunk ch get ~2 epochs + issue
  // lead to land -> ~9-14 KB in flight per CU at 3 blocks/CU. ----
  int bcur = 0;
  for (int ch = 0; ch < NCHUNK; ++ch) {
    if (ch == NCHUNK - 1) {
      asm volatile("s_waitcnt vmcnt(0)" ::: "memory");
    } else if (wvid == 0) {
      asm volatile("s_waitcnt vmcnt(2)" ::: "memory");
    } else {
      asm volatile("s_waitcnt vmcnt(1)" ::: "memory");
    }
    __builtin_amdgcn_s_barrier();

    if (ch + 2 < NCHUNK) {
      int bnxt = bcur + 2; if (bnxt >= NSTG) bnxt -= NSTG;
      stage_chunk(ch + 2, stage[bnxt]);
    }
    {
      // 4 channels/chunk across 8 groups: g and g^4 duplicate (same channel,
      // same point, identical math -> benign same-value LDS dup-write).
      const float* sp = stage[bcur] + (g & 3) * (MT * NK) + p * NK;
      float f[9];
#pragma unroll
      for (int k = 0; k < NK; ++k) f[k] = sp[k];
      const int c = 2 + ch * CHC + (g & 3);  // concat channel index
      unsigned short* wr = wfs + p * ROWE + c * 9;
#pragma unroll
      for (int o = 0; o < 9; ++o) {
        float s = wv[o][0] * f[0];
#pragma unroll
        for (int k = 1; k < NK; ++k) s += wv[o][k] * f[k];
        wr[o] = f2bf(s);
      }
    }
    bcur = (bcur == NSTG - 1) ? 0 : bcur + 1;
  }
  __syncthreads();  // full drain + publish wfs for phase 2

  // ---- Phase 2: [32 pts x 608] @ [608 x 64 co] via mfma_f32_16x16x32_bf16 ----
  const unsigned int* wfu = (const unsigned int*)wfs;
  const int r    = wvid & 1;     // row-tile: points [16r, 16r+16)
  const int hh   = wvid >> 1;    // col half: co tiles {2hh, 2hh+1}
  const int col  = lane & 15;
  const int q    = lane >> 4;

  frag4 acc[2];
#pragma unroll
  for (int ct = 0; ct < 2; ++ct) acc[ct] = frag4{0.f, 0.f, 0.f, 0.f};

  const int arow_u = (16 * r + col) * ROWU;

  for (int s = 0; s < KPAD / 32; ++s) {
    const int k0 = 32 * s;
    union { unsigned int u[4]; frag8 v; } ua;
    const int abase = arow_u + ((k0 + q * 8) >> 1);
    ua.u[0] = wfu[abase + 0];
    ua.u[1] = wfu[abase + 1];
    ua.u[2] = wfu[abase + 2];
    ua.u[3] = wfu[abase + 3];
#pragma unroll
    for (int ct = 0; ct < 2; ++ct) {
      const frag8* bp = (const frag8*)(lb + ((2 * hh + ct) * 16 + col) * KPAD + k0 + q * 8);
      acc[ct] = __builtin_amdgcn_mfma_f32_16x16x32_bf16(ua.v, *bp, acc[ct], 0, 0, 0);
    }
  }

  // ---- Epilogue: bias + leaky, float4 stores (D: col -> co, row = q*4+reg -> point) ----
  float* outbase = out + ((size_t)b * NCO) * NN;
  const int nrow = n0 + 16 * r + q * 4;
#pragma unroll
  for (int ct = 0; ct < 2; ++ct) {
    const int co = (2 * hh + ct) * 16 + col;
    const float bias = lin_b[co];
    float4 v;
    v.x = leakyf(acc[ct][0] + bias);
    v.y = leakyf(acc[ct][1] + bias);
    v.z = leakyf(acc[ct][2] + bias);
    v.w = leakyf(acc[ct][3] + bias);
    *(float4*)(outbase + (size_t)co * NN + nrow) = v;
  }
}

extern "C" void kernel_launch(void* const* d_in, const int* in_sizes, int n_in,
                              void* d_out, int out_size, void* d_ws, size_t ws_size,
                              hipStream_t stream) {
  const float* xy    = (const float*)d_in[0];
  const float* feat  = (const float*)d_in[1];
  const float* w1    = (const float*)d_in[2];
  const float* b1    = (const float*)d_in[3];
  const float* w2    = (const float*)d_in[4];
  const float* b2    = (const float*)d_in[5];
  const float* lw    = (const float*)d_in[6];
  const float* lbias = (const float*)d_in[7];
  float* out = (float*)d_out;
  unsigned short* lb = (unsigned short*)d_ws; // 64*608*2 = 77824 B

  prep_lb_kernel<<<(NCO * KPAD + 255) / 256, 256, 0, stream>>>(lw, lb);
  pointconv_kernel<<<NB * (NN / MT), 256, 0, stream>>>(
      xy, feat, w1, b1, w2, b2, lb, lbias, out);
}

// Round 10
// 465.369 us; speedup vs baseline: 1.0927x; 1.0927x over previous
//
#include <hip/hip_runtime.h>
#include <hip/hip_bf16.h>

// Problem constants (from reference setup_inputs)
#define NB   8
#define NN   16384
#define NK   9
#define NCF  64          // feature channels
#define NCIN 66          // 2 + 64 concat channels
#define NCO  64
#define JTOT (NCIN * NK) // 594
#define KPAD 608         // 19 * 32 (MFMA K-steps)
#define ROWE 610         // LDS wf row length in bf16 elems (odd dword stride -> conflict-free)
#define ROWU (ROWE / 2)  // 305 uints per row
#define MT   32          // points per block

typedef __attribute__((ext_vector_type(8))) short frag8;  // 8 bf16 (4 VGPRs)
typedef __attribute__((ext_vector_type(4))) float frag4;  // 4 fp32 acc

__device__ __forceinline__ float leakyf(float x) { return fmaxf(x, 0.1f * x); }

// bf16 RNE — the proven numerics path (absmax 0.125). Math/FMA order is
// bit-identical to the passing R1 kernel. ONLY the feat path changed:
// per-thread direct global->register loads (each feat value has exactly one
// consumer thread -> no reuse -> LDS staging + its 8-16 barrier epochs were
// pure latency exposure; R6 counters: VALU 32 / Occ 22 / HBM 11.5 -> latency
// bound). vs R7 (failed 0.484): removed __launch_bounds__(256,4) VGPR cap
// (spill-codegen suspect) and the manual fc/fn rotation — plain per-channel
// load->compute->store; compiler handles pipelining with correct waits.
__device__ __forceinline__ unsigned short f2bf(float x) {
  __hip_bfloat16 h = __float2bfloat16(x);
  unsigned short us;
  __builtin_memcpy(&us, &h, 2);
  return us;
}

// Repack lin_w [64][594] fp32 (row co, col o*66+c) into bf16 lb[co][j], j = c*9+o, zero-padded to 608.
__global__ void prep_lb_kernel(const float* __restrict__ lin_w, unsigned short* __restrict__ lb) {
  int idx = blockIdx.x * 256 + threadIdx.x;
  if (idx >= NCO * KPAD) return;
  int co = idx / KPAD;
  int j  = idx - co * KPAD;
  float v = 0.f;
  if (j < JTOT) {
    int c = j / NK;
    int o = j - c * NK;
    v = lin_w[co * JTOT + o * NCIN + c];
  }
  lb[idx] = f2bf(v);
}

__global__ __launch_bounds__(256) void pointconv_kernel(
    const float* __restrict__ xy,   // [8][2][16384][9]
    const float* __restrict__ feat, // [8][64][16384][9]
    const float* __restrict__ w1,   // [9][2]
    const float* __restrict__ b1,   // [9]
    const float* __restrict__ w2,   // [9][9]
    const float* __restrict__ b2,   // [9]
    const unsigned short* __restrict__ lb, // bf16 [64][608]
    const float* __restrict__ lin_b,       // [64]
    float* __restrict__ out) {             // [8][64][16384]
  __shared__ unsigned short wfs[MT * ROWE]; // 39,040 B — ONLY LDS -> 4 blocks/CU

  const int t    = threadIdx.x;
  const int p    = t & 31;          // point within tile
  const int g    = t >> 5;          // channel group 0..7 (8 channels each)
  const int lane = t & 63;
  const int wvid = t >> 6;          // wave id 0..3
  const int b    = blockIdx.x >> 9; // 512 tiles per batch
  const int n0   = (blockIdx.x & 511) << 5;
  const int n    = n0 + p;

  // ---- xy loads (registers) ----
  float x0[9], x1[9];
  {
    const float* x0p = xy + (((size_t)b * 2 + 0) * NN + n) * NK;
    const float* x1p = xy + (((size_t)b * 2 + 1) * NN + n) * NK;
#pragma unroll
    for (int k = 0; k < NK; ++k) { x0[k] = x0p[k]; x1[k] = x1p[k]; }
  }

  // ---- Phase 1a: WeightNet -> wv[9][9] (registers; math identical) ----
  float wv[9][9];
#pragma unroll
  for (int k = 0; k < NK; ++k) {
    float h[9];
#pragma unroll
    for (int o = 0; o < 9; ++o)
      h[o] = leakyf(w1[2 * o] * x0[k] + w1[2 * o + 1] * x1[k] + b1[o]);
#pragma unroll
    for (int o = 0; o < 9; ++o) {
      float s = b2[o];
#pragma unroll
      for (int o2 = 0; o2 < 9; ++o2) s += w2[o * 9 + o2] * h[o2];
      wv[o][k] = leakyf(s);
    }
  }

  // ---- xy channels (concat c=0,1) from registers; zero-pad tail ----
  if (g == 0) {
#pragma unroll
    for (int cc = 0; cc < 2; ++cc) {
#pragma unroll
      for (int o = 0; o < 9; ++o) {
        float s = wv[o][0] * (cc ? x1[0] : x0[0]);
#pragma unroll
        for (int k = 1; k < NK; ++k) s += wv[o][k] * (cc ? x1[k] : x0[k]);
        wfs[p * ROWE + cc * 9 + o] = f2bf(s);
      }
    }
  }
  if (g == 1) {
#pragma unroll
    for (int m = 0; m < KPAD - JTOT; ++m) wfs[p * ROWE + JTOT + m] = 0;
  }

  // ---- Phase 1b: 8 feat channels per thread, direct global->register.
  // Channel cc -> feat channel cc*8+g -> concat c = 2 + cc*8 + g (the exact
  // bijection of the passing staged kernels; same FMA order -> same bits).
  // One wave = 2 channels x 32 points = 2 contiguous 1152B regions per dword
  // step -> lines fully consumed across the 9 loads (L1-resident). Compiler
  // hoists next-iteration loads across the unrolled body with its own
  // counted waitcnts; zero barriers until the single publish below. ----
  {
    const float* fbase = feat + (((size_t)b * NCF + g) * NN + (size_t)n) * NK;
#pragma unroll
    for (int cc = 0; cc < 8; ++cc) {
      const float* fp = fbase + (size_t)(cc * 8) * ((size_t)NN * NK);
      float f[9];
#pragma unroll
      for (int k = 0; k < NK; ++k) f[k] = fp[k];
      const int c = 2 + cc * 8 + g;
      unsigned short* wr = wfs + p * ROWE + c * 9;
#pragma unroll
      for (int o = 0; o < 9; ++o) {
        float s = wv[o][0] * f[0];
#pragma unroll
        for (int k = 1; k < NK; ++k) s += wv[o][k] * f[k];
        wr[o] = f2bf(s);
      }
    }
  }

  __syncthreads();  // single barrier: publish wfs for phase 2

  // ---- Phase 2: [32 pts x 608] @ [608 x 64 co] via mfma_f32_16x16x32_bf16 ----
  const unsigned int* wfu = (const unsigned int*)wfs;
  const int r    = wvid & 1;     // row-tile: points [16r, 16r+16)
  const int hh   = wvid >> 1;    // col half: co tiles {2hh, 2hh+1}
  const int col  = lane & 15;
  const int q    = lane >> 4;

  frag4 acc[2];
#pragma unroll
  for (int ct = 0; ct < 2; ++ct) acc[ct] = frag4{0.f, 0.f, 0.f, 0.f};

  const int arow_u = (16 * r + col) * ROWU;

  for (int s = 0; s < KPAD / 32; ++s) {
    const int k0 = 32 * s;
    union { unsigned int u[4]; frag8 v; } ua;
    const int abase = arow_u + ((k0 + q * 8) >> 1);
    ua.u[0] = wfu[abase + 0];
    ua.u[1] = wfu[abase + 1];
    ua.u[2] = wfu[abase + 2];
    ua.u[3] = wfu[abase + 3];
#pragma unroll
    for (int ct = 0; ct < 2; ++ct) {
      const frag8* bp = (const frag8*)(lb + ((2 * hh + ct) * 16 + col) * KPAD + k0 + q * 8);
      acc[ct] = __builtin_amdgcn_mfma_f32_16x16x32_bf16(ua.v, *bp, acc[ct], 0, 0, 0);
    }
  }

  // ---- Epilogue: bias + leaky, float4 stores (D: col -> co, row = q*4+reg -> point) ----
  float* outbase = out + ((size_t)b * NCO) * NN;
  const int nrow = n0 + 16 * r + q * 4;
#pragma unroll
  for (int ct = 0; ct < 2; ++ct) {
    const int co = (2 * hh + ct) * 16 + col;
    const float bias = lin_b[co];
    float4 v;
    v.x = leakyf(acc[ct][0] + bias);
    v.y = leakyf(acc[ct][1] + bias);
    v.z = leakyf(acc[ct][2] + bias);
    v.w = leakyf(acc[ct][3] + bias);
    *(float4*)(outbase + (size_t)co * NN + nrow) = v;
  }
}

extern "C" void kernel_launch(void* const* d_in, const int* in_sizes, int n_in,
                              void* d_out, int out_size, void* d_ws, size_t ws_size,
                              hipStream_t stream) {
  const float* xy    = (const float*)d_in[0];
  const float* feat  = (const float*)d_in[1];
  const float* w1    = (const float*)d_in[2];
  const float* b1    = (const float*)d_in[3];
  const float* w2    = (const float*)d_in[4];
  const float* b2    = (const float*)d_in[5];
  const float* lw    = (const float*)d_in[6];
  const float* lbias = (const float*)d_in[7];
  float* out = (float*)d_out;
  unsigned short* lb = (unsigned short*)d_ws; // 64*608*2 = 77824 B

  prep_lb_kernel<<<(NCO * KPAD + 255) / 256, 256, 0, stream>>>(lw, lb);
  pointconv_kernel<<<NB * (NN / MT), 256, 0, stream>>>(
      xy, feat, w1, b1, w2, b2, lb, lbias, out);
}